// Round 6
// baseline (845.095 us; speedup 1.0000x reference)
//
#include <hip/hip_runtime.h>
#include <hip/hip_bf16.h>

// ============================================================================
// ROUND 6 = COUNTER-VISIBILITY PROBE. gemm body looped REPS=16 inside ONE
// dispatch (~500us) so it beats the ~310us harness fills into rocprof top-5.
// Two variants: DBUF=0 (r4 baseline structure) runs first; DBUF=1
// (double-buffered stage, T3-minimum: prefetch next chunk before computing
// current, raw s_barrier + explicit vmcnt(0), 1 barrier/chunk) runs LAST so
// validation checks its correctness. Revert to single launch next round.
// ============================================================================

#define BATCH   8192
#define NGRP    8
#define MAXGS   64
#define DMODEL  2048
#define TILES   512
#define SPLITK  4
#define KC      512
#define NCHUNK  (DMODEL / KC)   // 4
#define REPS    16

typedef __attribute__((ext_vector_type(8))) short  short8;
typedef __attribute__((ext_vector_type(4))) float  f32x4;

#define LISTS_OFF 1024
#define W_OFF (LISTS_OFF + NGRP * BATCH * 4)
#define CNT_STRIDE 16

static __device__ __forceinline__ short bf(float f) {
    __hip_bfloat16 h = __float2bfloat16(f);
    return (short)__bfloat16_as_ushort(h);
}

static __device__ __forceinline__ void gload_lds16(const float* src, float* lds) {
    __builtin_amdgcn_global_load_lds(
        (const __attribute__((address_space(1))) unsigned int*)src,
        (__attribute__((address_space(3))) unsigned int*)lds,
        16, 0, 0);
}

__global__ __launch_bounds__(256) void init_kernel(const float* __restrict__ W,
                                                   unsigned short* __restrict__ Wb,
                                                   int* __restrict__ cnt) {
    int idx = blockIdx.x * 256 + threadIdx.x;
    if (idx < NGRP * CNT_STRIDE) cnt[idx] = 0;
    int e = idx * 4;
    float4 w = *reinterpret_cast<const float4*>(W + e);
    ushort4 o;
    o.x = (unsigned short)bf(w.x); o.y = (unsigned short)bf(w.y);
    o.z = (unsigned short)bf(w.z); o.w = (unsigned short)bf(w.w);
    *reinterpret_cast<ushort4*>(Wb + e) = o;
}

__global__ __launch_bounds__(256) void bucket_kernel(const int* __restrict__ chosen,
                                                     int* __restrict__ cnt,
                                                     int* __restrict__ lists) {
    __shared__ int lcnt[NGRP];
    __shared__ int lbase[NGRP];
    int tid = threadIdx.x;
    int b = blockIdx.x * 256 + tid;
    int g = chosen[b];
    int lane = tid & 63;
    if (tid < NGRP) lcnt[tid] = 0;
    __syncthreads();

    int wbase = 0;
    unsigned long long mymask = 0;
    #pragma unroll
    for (int gg = 0; gg < NGRP; ++gg) {
        unsigned long long m = __ballot(g == gg);
        if (g == gg) {
            int leader = __ffsll(m) - 1;
            int wb_ = 0;
            if (lane == leader) wb_ = atomicAdd(&lcnt[gg], __popcll(m));
            wb_ = __shfl(wb_, leader);
            wbase = wb_;
            mymask = m;
        }
    }
    __syncthreads();
    if (tid < NGRP) lbase[tid] = atomicAdd(&cnt[tid * CNT_STRIDE], lcnt[tid]);
    __syncthreads();

    int pos = lbase[g] + wbase + __popcll(mymask & ((1ull << lane) - 1ull));
    lists[g * BATCH + pos] = b;
}

// DBUF=0: exact r4 structure (stage -> sync -> compute -> sync), REPS-looped.
// DBUF=1: 2-buffer pipeline; stage(ch+1) issued BEFORE compute(ch); explicit
//         s_waitcnt vmcnt(0) + raw s_barrier once per chunk.
template<int DBUF>
__global__ __launch_bounds__(256, 3 - DBUF) void gemm_probe(
    const float* __restrict__ hidden,
    const float* __restrict__ bias,
    const int* __restrict__ gsizes,
    const int* __restrict__ cnt,
    const int* __restrict__ lists,
    const unsigned short* __restrict__ Wb,
    float* __restrict__ out)
{
    int bid = blockIdx.x;
    int g = bid & (NGRP - 1);
    int t = bid >> 3;
    int c = cnt[g * CNT_STRIDE];
    int m0 = t << 4;
    if (m0 >= c) return;

    union Smem {
        float A[DBUF + 1][16][KC];       // 32 or 64 KB
        float red[SPLITK][64][17];       // overlay, used after last compute
    };
    __shared__ Smem sm;

    int tid  = threadIdx.x;
    int w    = tid >> 6;
    int lane = tid & 63;
    int lrow = lane & 15;
    int kg   = lane >> 4;
    int swr  = (lrow & 7) << 4;

    const float* hbase[4];
    #pragma unroll
    for (int i = 0; i < 4; ++i) {
        int m  = m0 + w * 4 + i;
        int ms = m < c ? m : c - 1;
        int smp = lists[g * BATCH + ms];
        hbase[i] = hidden + ((size_t)smp * NGRP + g) * DMODEL;
    }

    int gsz = gsizes[g];

    for (int rep = 0; rep < REPS; ++rep) {
        f32x4 acc[4] = {f32x4{0,0,0,0}, f32x4{0,0,0,0}, f32x4{0,0,0,0}, f32x4{0,0,0,0}};

        auto STAGE = [&](int buf, int ch) {
            #pragma unroll
            for (int i = 0; i < 4; ++i) {
                int r  = w * 4 + i;
                int sw = (r & 7) << 4;
                const float* src = hbase[i] + ch * KC;
                #pragma unroll
                for (int h = 0; h < 2; ++h) {
                    int lb = (h * 1024 + lane * 16) ^ sw;
                    gload_lds16(src + (lb >> 2), &sm.A[buf][r][h * 256]);
                }
            }
        };
        auto COMPUTE = [&](int buf, int ch) {
            #pragma unroll
            for (int kk = 0; kk < 4; ++kk) {
                int xb = w * 512 + kk * 128 + kg * 32;
                const char* arow = (const char*)&sm.A[buf][lrow][0];
                f32x4 alo = *reinterpret_cast<const f32x4*>(arow + ((xb) ^ swr));
                f32x4 ahi = *reinterpret_cast<const f32x4*>(arow + ((xb + 16) ^ swr));
                short8 af;
                af[0] = bf(alo[0]); af[1] = bf(alo[1]); af[2] = bf(alo[2]); af[3] = bf(alo[3]);
                af[4] = bf(ahi[0]); af[5] = bf(ahi[1]); af[6] = bf(ahi[2]); af[7] = bf(ahi[3]);
                int kglob = ch * KC + w * 128 + kk * 32 + kg * 8;
                const unsigned short* wbp = Wb + ((size_t)g * MAXGS + lrow) * DMODEL + kglob;
                short8 b0 = *reinterpret_cast<const short8*>(wbp);
                short8 b1 = *reinterpret_cast<const short8*>(wbp + 16 * DMODEL);
                short8 b2 = *reinterpret_cast<const short8*>(wbp + 32 * DMODEL);
                short8 b3 = *reinterpret_cast<const short8*>(wbp + 48 * DMODEL);
                acc[0] = __builtin_amdgcn_mfma_f32_16x16x32_bf16(af, b0, acc[0], 0, 0, 0);
                acc[1] = __builtin_amdgcn_mfma_f32_16x16x32_bf16(af, b1, acc[1], 0, 0, 0);
                acc[2] = __builtin_amdgcn_mfma_f32_16x16x32_bf16(af, b2, acc[2], 0, 0, 0);
                acc[3] = __builtin_amdgcn_mfma_f32_16x16x32_bf16(af, b3, acc[3], 0, 0, 0);
            }
        };

        if constexpr (!DBUF) {
            for (int ch = 0; ch < NCHUNK; ++ch) {
                STAGE(0, ch);
                __syncthreads();
                COMPUTE(0, ch);
                __syncthreads();
            }
        } else {
            STAGE(0, 0);
            asm volatile("s_waitcnt vmcnt(0)" ::: "memory");
            __builtin_amdgcn_s_barrier();
            #pragma unroll
            for (int ch = 0; ch < NCHUNK; ++ch) {
                if (ch + 1 < NCHUNK) STAGE((ch + 1) & 1, ch + 1);  // prefetch
                COMPUTE(ch & 1, ch);                                // hides latency
                asm volatile("s_waitcnt vmcnt(0)" ::: "memory");    // next buf landed
                __builtin_amdgcn_s_barrier();                       // all waves done
            }
        }

        // split-K reduce (red overlays A; ordered by the barrier above)
        #pragma unroll
        for (int ti = 0; ti < 4; ++ti)
            #pragma unroll
            for (int r = 0; r < 4; ++r)
                sm.red[w][lane][ti * 4 + r] = acc[ti][r];
        __syncthreads();

        #pragma unroll
        for (int i = 0; i < 4; ++i) {
            int o  = tid + i * 256;
            int ml = o >> 6;
            int n  = o & 63;
            int rl = ((ml >> 2) << 4) | (n & 15);
            int e  = ((n >> 4) << 2) | (ml & 3);
            float s = sm.red[0][rl][e] + sm.red[1][rl][e]
                    + sm.red[2][rl][e] + sm.red[3][rl][e];
            int m = m0 + ml;
            if (m < c) {
                int smp = lists[g * BATCH + m];
                out[(size_t)smp * MAXGS + n] = s + bias[g * MAXGS + n];
                out[(size_t)(BATCH + smp) * MAXGS + n] = (n < gsz) ? 1.0f : 0.0f;
            }
        }
        __syncthreads();   // protect red/A overlay across reps
    }
}

extern "C" void kernel_launch(void* const* d_in, const int* in_sizes, int n_in,
                              void* d_out, int out_size, void* d_ws, size_t ws_size,
                              hipStream_t stream) {
    const float* hidden = (const float*)d_in[0];
    const int*   chosen = (const int*)d_in[1];
    const float* W      = (const float*)d_in[2];
    const float* bias   = (const float*)d_in[3];
    const int*   gs     = (const int*)d_in[4];
    float* out = (float*)d_out;

    char* ws = (char*)d_ws;
    int* cnt   = (int*)ws;
    int* lists = (int*)(ws + LISTS_OFF);
    unsigned short* Wb = (unsigned short*)(ws + W_OFF);

    init_kernel<<<dim3(1024), dim3(256), 0, stream>>>(W, Wb, cnt);
    bucket_kernel<<<dim3(32), dim3(256), 0, stream>>>(chosen, cnt, lists);
    // Baseline probe first (counters), dbuf variant LAST (validated output).
    gemm_probe<0><<<dim3(NGRP * TILES), dim3(256), 0, stream>>>(
        hidden, bias, gs, cnt, lists, Wb, out);
    gemm_probe<1><<<dim3(NGRP * TILES), dim3(256), 0, stream>>>(
        hidden, bias, gs, cnt, lists, Wb, out);
}

// Round 7
// 56.238 us; speedup vs baseline: 15.0270x; 15.0270x over previous
//
#include <hip/hip_runtime.h>
#include <hip/hip_bf16.h>

// Problem constants
#define BATCH   8192
#define NGRP    8
#define MAXGS   64
#define DMODEL  2048

// gemm geometry: 8-sample x 64-out tiles, 4 waves n-split, ring-buffered A.
#define TM      8                 // samples per tile
#define KC      128               // f32 per chunk-row
#define NPH     (DMODEL / KC)     // 16 phases
#define RING    8                 // LDS ring buffers (8 x 4KB = 32KB)
#define PF      6                 // prefetch depth (stage ch+6 in phase ch)

typedef __attribute__((ext_vector_type(8))) short  short8;
typedef __attribute__((ext_vector_type(4))) float  f32x4;

#define LISTS_OFF 1024
#define W_OFF (LISTS_OFF + NGRP * BATCH * 4)
#define CNT_STRIDE 16   // ints; 64B line per counter

static __device__ __forceinline__ short bf(float f) {
    __hip_bfloat16 h = __float2bfloat16(f);
    return (short)__bfloat16_as_ushort(h);
}

// async global->LDS DMA, 16B/lane; dest = wave-uniform base + lane*16 (linear)
static __device__ __forceinline__ void gload_lds16(const float* src, float* lds) {
    __builtin_amdgcn_global_load_lds(
        (const __attribute__((address_space(1))) unsigned int*)src,
        (__attribute__((address_space(3))) unsigned int*)lds,
        16, 0, 0);
}

// Phase 0: zero padded counters + convert W (f32 -> bf16) into ws.
__global__ __launch_bounds__(256) void init_kernel(const float* __restrict__ W,
                                                   unsigned short* __restrict__ Wb,
                                                   int* __restrict__ cnt) {
    int idx = blockIdx.x * 256 + threadIdx.x;
    if (idx < NGRP * CNT_STRIDE) cnt[idx] = 0;
    int e = idx * 4;
    float4 w = *reinterpret_cast<const float4*>(W + e);
    ushort4 o;
    o.x = (unsigned short)bf(w.x); o.y = (unsigned short)bf(w.y);
    o.z = (unsigned short)bf(w.z); o.w = (unsigned short)bf(w.w);
    *reinterpret_cast<ushort4*>(Wb + e) = o;
}

// Phase 1: bucket samples by group (LDS-aggregated atomics; order
// nondeterministic, per-sample output values order-independent).
__global__ __launch_bounds__(256) void bucket_kernel(const int* __restrict__ chosen,
                                                     int* __restrict__ cnt,
                                                     int* __restrict__ lists) {
    __shared__ int lcnt[NGRP];
    __shared__ int lbase[NGRP];
    int tid = threadIdx.x;
    int b = blockIdx.x * 256 + tid;
    int g = chosen[b];
    int lane = tid & 63;
    if (tid < NGRP) lcnt[tid] = 0;
    __syncthreads();

    int wbase = 0;
    unsigned long long mymask = 0;
    #pragma unroll
    for (int gg = 0; gg < NGRP; ++gg) {
        unsigned long long m = __ballot(g == gg);
        if (g == gg) {
            int leader = __ffsll(m) - 1;
            int wb_ = 0;
            if (lane == leader) wb_ = atomicAdd(&lcnt[gg], __popcll(m));
            wb_ = __shfl(wb_, leader);
            wbase = wb_;
            mymask = m;
        }
    }
    __syncthreads();
    if (tid < NGRP) lbase[tid] = atomicAdd(&cnt[tid * CNT_STRIDE], lcnt[tid]);
    __syncthreads();

    int pos = lbase[g] + wbase + __popcll(mymask & ((1ull << lane) - 1ull));
    lists[g * BATCH + pos] = b;
}

// Phase 2 (redesigned from r6 counters: all pipes idle, occupancy 15% ->
// latency-bound). 8-sample tiles -> 1024 active blocks (4/CU, 16 waves/CU).
// Waves split N (16 cols each, full K) -> no split-K reduce, acc = 1 f32x4.
// A staged in a ring of 8 x [8][KC] f32 buffers, prefetch depth 6, ONE raw
// s_barrier per phase and NO vmcnt drain in the loop: stage(ch) retirement
// is implied by the compiler's waits on compute(ch-1)'s B-loads (issued
// after stage(ch); vmcnt retires in order). Loads stay in flight across
// barriers -> gather latency hidden by ~6 phases of compute.
// A-row swizzle: LDS[row][x] = global[row][x ^ ((row&7)<<4)] via pre-swizzled
// per-lane global source (DMA dest stays linear); reads XOR the same.
__global__ __launch_bounds__(256, 4) void gemm_kernel(
    const float* __restrict__ hidden,
    const float* __restrict__ bias,
    const int* __restrict__ gsizes,
    const int* __restrict__ cnt,
    const int* __restrict__ lists,
    const unsigned short* __restrict__ Wb,
    float* __restrict__ out)
{
    int bid = blockIdx.x;
    int g = bid & (NGRP - 1);      // bid&7 <-> XCD round-robin: each XCD sees
    int t = bid >> 3;              // mostly one group's Wb (L2-resident)
    int c = cnt[g * CNT_STRIDE];
    int m0 = t * TM;
    if (m0 >= c) return;           // inactive tile: uniform exit

    __shared__ float A[RING][TM][KC];   // 32 KB

    int tid  = threadIdx.x;
    int w    = tid >> 6;           // wave id 0..3 -> n-slice [16w, 16w+16)
    int lane = tid & 63;
    int lrow = lane & 15;
    int kg   = lane >> 4;          // 0..3

    // --- staging geometry: wave w stages rows 2w (lanes 0-31), 2w+1 (32-63)
    int r0 = 2 * w + (lane >> 5);
    int ms = m0 + r0 < c ? m0 + r0 : c - 1;     // tail: dup last row (writes guarded)
    const float* hb = hidden + ((size_t)lists[g * BATCH + ms] * NGRP + g) * DMODEL;
    int soff = (((lane & 31) * 16) ^ (r0 << 4)) >> 2;   // pre-swizzled src, f32 units

    // --- compute geometry
    int arow = lane & 7;               // LDS row for A-frag (rows 8-15 dup 0-7)
    int swz  = arow << 4;              // read-side XOR (bytes)
    const unsigned short* wbp0 =
        Wb + ((size_t)g * MAXGS + w * 16 + lrow) * DMODEL + kg * 8;

    f32x4 acc = f32x4{0, 0, 0, 0};

    auto STAGE = [&](int ph) {
        gload_lds16(hb + ph * KC + soff, &A[ph & (RING - 1)][2 * w][0]);
    };

    // prologue: fill depth-PF pipeline; one explicit wait for stage(0)
    #pragma unroll
    for (int ph = 0; ph < PF; ++ph) STAGE(ph);
    asm volatile("s_waitcnt vmcnt(%0)" :: "i"(PF - 1) : "memory");
    __builtin_amdgcn_s_barrier();

    #pragma unroll
    for (int ch = 0; ch < NPH; ++ch) {
        if (ch + PF < NPH) STAGE(ch + PF);
        // buffer (ch&7): stage(ch) already retired (see header comment);
        // barrier at end of previous iteration made all waves' rows visible.
        const char* ab = (const char*)&A[ch & (RING - 1)][arow][0];
        #pragma unroll
        for (int kk = 0; kk < KC / 32; ++kk) {
            int xb = kk * 128 + kg * 32;
            f32x4 alo = *reinterpret_cast<const f32x4*>(ab + ((xb) ^ swz));
            f32x4 ahi = *reinterpret_cast<const f32x4*>(ab + ((xb + 16) ^ swz));
            short8 af;
            af[0] = bf(alo[0]); af[1] = bf(alo[1]); af[2] = bf(alo[2]); af[3] = bf(alo[3]);
            af[4] = bf(ahi[0]); af[5] = bf(ahi[1]); af[6] = bf(ahi[2]); af[7] = bf(ahi[3]);
            short8 bfr = *reinterpret_cast<const short8*>(wbp0 + ch * KC + kk * 32);
            acc = __builtin_amdgcn_mfma_f32_16x16x32_bf16(af, bfr, acc, 0, 0, 0);
        }
        __builtin_amdgcn_s_barrier();   // raw barrier: no vmcnt drain; ring
                                        // depth 8 > PF+1 keeps writes safe
    }

    // --- epilogue: C row = (lane>>4)*4 + r; only rows 0-7 are real samples
    int row4 = lane >> 4;
    if (row4 < 2) {
        int gsz = gsizes[g];
        int n = w * 16 + lrow;
        float bv = bias[g * MAXGS + n];
        #pragma unroll
        for (int r = 0; r < 4; ++r) {
            int m = m0 + row4 * 4 + r;
            if (m < c) {
                int smp = lists[g * BATCH + m];
                out[(size_t)smp * MAXGS + n] = acc[r] + bv;   // padded n: 0+0 == 0
                out[(size_t)(BATCH + smp) * MAXGS + n] = (n < gsz) ? 1.0f : 0.0f;
            }
        }
    }
}

extern "C" void kernel_launch(void* const* d_in, const int* in_sizes, int n_in,
                              void* d_out, int out_size, void* d_ws, size_t ws_size,
                              hipStream_t stream) {
    const float* hidden = (const float*)d_in[0];   // [8192, 8, 2048] f32
    const int*   chosen = (const int*)d_in[1];     // [8192] i32
    const float* W      = (const float*)d_in[2];   // [8, 64, 2048] f32 (zero-padded)
    const float* bias   = (const float*)d_in[3];   // [8, 64] f32 (zero-padded)
    const int*   gs     = (const int*)d_in[4];     // [8] i32
    float* out = (float*)d_out;                    // [8192*64 preds | 8192*64 valid]

    char* ws = (char*)d_ws;
    int* cnt   = (int*)ws;
    int* lists = (int*)(ws + LISTS_OFF);
    unsigned short* Wb = (unsigned short*)(ws + W_OFF);

    init_kernel<<<dim3(1024), dim3(256), 0, stream>>>(W, Wb, cnt);
    bucket_kernel<<<dim3(32), dim3(256), 0, stream>>>(chosen, cnt, lists);
    gemm_kernel<<<dim3(NGRP * (BATCH / TM)), dim3(256), 0, stream>>>(
        hidden, bias, gs, cnt, lists, Wb, out);
}

// Round 8
// 44.087 us; speedup vs baseline: 19.1690x; 1.2756x over previous
//
#include <hip/hip_runtime.h>
#include <hip/hip_bf16.h>

// Problem constants
#define BATCH   8192
#define NGRP    8
#define MAXGS   64
#define DMODEL  2048

// gemm geometry: 16-sample x 64-col tiles; 2 producer + 4 consumer waves.
#define TM      16                // samples per tile
#define KC      128               // f32 per phase
#define NPH     (DMODEL / KC)     // 16 phases
#define RING    8                 // 8 x [16][128] f32 = 64 KB
#define PFD     6                 // prefetch depth (phases)
#define PWAVES  2
#define CWAVES  4
#define NTHR    ((PWAVES + CWAVES) * 64)   // 384

typedef __attribute__((ext_vector_type(8))) short  short8;
typedef __attribute__((ext_vector_type(4))) float  f32x4;

#define LISTS_OFF 1024
#define W_OFF (LISTS_OFF + NGRP * BATCH * 4)
#define CNT_STRIDE 16   // ints; 64B line per counter

static __device__ __forceinline__ short bf(float f) {
    __hip_bfloat16 h = __float2bfloat16(f);
    return (short)__bfloat16_as_ushort(h);
}

// async global->LDS DMA, 16B/lane; dest wave-uniform base + lane*16 (linear);
// SOURCE address is per-lane (pre-swizzled gather).
static __device__ __forceinline__ void gload_lds16(const float* src, float* lds) {
    __builtin_amdgcn_global_load_lds(
        (const __attribute__((address_space(1))) unsigned int*)src,
        (__attribute__((address_space(3))) unsigned int*)lds,
        16, 0, 0);
}

// Phase 0: zero padded counters + convert W (f32 -> bf16) into ws.
__global__ __launch_bounds__(256) void init_kernel(const float* __restrict__ W,
                                                   unsigned short* __restrict__ Wb,
                                                   int* __restrict__ cnt) {
    int idx = blockIdx.x * 256 + threadIdx.x;
    if (idx < NGRP * CNT_STRIDE) cnt[idx] = 0;
    int e = idx * 4;
    float4 w = *reinterpret_cast<const float4*>(W + e);
    ushort4 o;
    o.x = (unsigned short)bf(w.x); o.y = (unsigned short)bf(w.y);
    o.z = (unsigned short)bf(w.z); o.w = (unsigned short)bf(w.w);
    *reinterpret_cast<ushort4*>(Wb + e) = o;
}

// Phase 1: bucket samples by group (LDS-aggregated atomics; order
// nondeterministic, per-sample output values order-independent).
__global__ __launch_bounds__(256) void bucket_kernel(const int* __restrict__ chosen,
                                                     int* __restrict__ cnt,
                                                     int* __restrict__ lists) {
    __shared__ int lcnt[NGRP];
    __shared__ int lbase[NGRP];
    int tid = threadIdx.x;
    int b = blockIdx.x * 256 + tid;
    int g = chosen[b];
    int lane = tid & 63;
    if (tid < NGRP) lcnt[tid] = 0;
    __syncthreads();

    int wbase = 0;
    unsigned long long mymask = 0;
    #pragma unroll
    for (int gg = 0; gg < NGRP; ++gg) {
        unsigned long long m = __ballot(g == gg);
        if (g == gg) {
            int leader = __ffsll(m) - 1;
            int wb_ = 0;
            if (lane == leader) wb_ = atomicAdd(&lcnt[gg], __popcll(m));
            wb_ = __shfl(wb_, leader);
            wbase = wb_;
            mymask = m;
        }
    }
    __syncthreads();
    if (tid < NGRP) lbase[tid] = atomicAdd(&cnt[tid * CNT_STRIDE], lcnt[tid]);
    __syncthreads();

    int pos = lbase[g] + wbase + __popcll(mymask & ((1ull << lane) - 1ull));
    lists[g * BATCH + pos] = b;
}

// Phase 2: producer/consumer gemm.
// WHY: A-prefetch (long-latency gather, needs depth) and B-loads (L2, per-use
// waits) in ONE wave share one in-order vmcnt queue -> any B wait drains the
// whole A prefetch (r4-r7 all hit this; DBUF A/B in r6 proved it). Split:
// producer waves issue ONLY global_load_lds with counted vmcnt(20) waits
// (never drain; ~20KB in flight each); consumer waves' only VMEM is B.
// Ring of 8 A-buffers, depth 6; ONE raw s_barrier per phase, no syncthreads.
// A swizzle: LDS[r][x] = global[r][x ^ ((r&7)<<4)] via pre-swizzled per-lane
// global source (DMA dest linear); consumers XOR the same on ds_read.
__global__ __launch_bounds__(NTHR, 3) void gemm_kernel(
    const float* __restrict__ hidden,
    const float* __restrict__ bias,
    const int* __restrict__ gsizes,
    const int* __restrict__ cnt,
    const int* __restrict__ lists,
    const unsigned short* __restrict__ Wb,
    float* __restrict__ out)
{
    int bid = blockIdx.x;
    int g = bid & (NGRP - 1);      // group <-> XCD alignment: Wb L2-resident
    int t = bid >> 3;
    int c = cnt[g * CNT_STRIDE];
    int m0 = t * TM;
    if (m0 >= c) return;           // uniform exit, before any barrier

    __shared__ float A[RING][TM][KC];   // 64 KB

    int tid  = threadIdx.x;
    int w    = tid >> 6;
    int lane = tid & 63;

    if (w < PWAVES) {
        // ---------------- PRODUCER: wave w stages rows 8w .. 8w+7 ----------
        // instr i covers rows 8w+2i (lanes 0-31) and 8w+2i+1 (lanes 32-63).
        int xsw = (lane & 31) * 16;    // within-row byte offset of this lane
        const float *hb0, *hb1, *hb2, *hb3;
        #define MKHB(i, dst)                                                   \
            {                                                                  \
                int r  = 8 * w + 2 * (i) + (lane >> 5);                        \
                int m  = m0 + r;                                               \
                int ms = m < c ? m : c - 1;   /* tail: dup last row */         \
                dst = hidden + ((size_t)lists[g * BATCH + ms] * NGRP + g) * DMODEL \
                      + ((xsw ^ ((r & 7) << 4)) >> 2);                         \
            }
        MKHB(0, hb0) MKHB(1, hb1) MKHB(2, hb2) MKHB(3, hb3)
        #undef MKHB

        #define PSTAGE(ph)                                                     \
            {                                                                  \
                float* dst = &A[(ph) & (RING - 1)][8 * w][0];                  \
                gload_lds16(hb0 + (ph) * KC, dst + 0 * 2 * KC);                \
                gload_lds16(hb1 + (ph) * KC, dst + 1 * 2 * KC);                \
                gload_lds16(hb2 + (ph) * KC, dst + 2 * 2 * KC);                \
                gload_lds16(hb3 + (ph) * KC, dst + 3 * 2 * KC);                \
            }
        #define PWAIT(n) asm volatile("s_waitcnt vmcnt(" #n ")" ::: "memory")
        #define PBAR()   __builtin_amdgcn_s_barrier(); asm volatile("" ::: "memory")

        // prologue: fill depth-6 pipeline; retire stage(0) only (24 -> 20)
        PSTAGE(0) PSTAGE(1) PSTAGE(2) PSTAGE(3) PSTAGE(4) PSTAGE(5)
        PWAIT(20);
        // phases 0..9: issue stage(ch+6); retire stage(ch+1); 20 stay in flight
        #define PPH(ch)  PBAR(); PSTAGE((ch) + PFD) PWAIT(20);
        PPH(0) PPH(1) PPH(2) PPH(3) PPH(4) PPH(5) PPH(6) PPH(7) PPH(8) PPH(9)
        #undef PPH
        // phases 10..15: no new issues; progressively retire stage(ch+1)
        PBAR(); PWAIT(16);   // ch=10: stage(11) done
        PBAR(); PWAIT(12);   // ch=11
        PBAR(); PWAIT(8);    // ch=12
        PBAR(); PWAIT(4);    // ch=13
        PBAR(); PWAIT(0);    // ch=14: stage(15) done
        PBAR();              // ch=15: consumers finish buffer 15
        #undef PSTAGE
        #undef PWAIT
        #undef PBAR
    } else {
        // ---------------- CONSUMER: wave cw owns cols [16cw, 16cw+16) ------
        int cw   = w - PWAVES;         // 0..3
        int lrow = lane & 15;
        int kg   = lane >> 4;          // 0..3
        int swzr = (lrow & 7) << 4;    // read-side XOR (bytes)
        const unsigned short* wbp0 =
            Wb + ((size_t)g * MAXGS + cw * 16 + lrow) * DMODEL + kg * 8;

        f32x4 acc = f32x4{0, 0, 0, 0};

        #pragma unroll
        for (int ch = 0; ch < NPH; ++ch) {
            __builtin_amdgcn_s_barrier();
            asm volatile("" ::: "memory");     // no LDS-read hoist above barrier
            const char* ab = (const char*)&A[ch & (RING - 1)][lrow][0];
            #pragma unroll
            for (int ks = 0; ks < KC / 32; ++ks) {
                int xb = ks * 128 + kg * 32;
                f32x4 alo = *reinterpret_cast<const f32x4*>(ab + ((xb) ^ swzr));
                f32x4 ahi = *reinterpret_cast<const f32x4*>(ab + ((xb + 16) ^ swzr));
                short8 af;
                af[0] = bf(alo[0]); af[1] = bf(alo[1]); af[2] = bf(alo[2]); af[3] = bf(alo[3]);
                af[4] = bf(ahi[0]); af[5] = bf(ahi[1]); af[6] = bf(ahi[2]); af[7] = bf(ahi[3]);
                short8 bfr = *reinterpret_cast<const short8*>(wbp0 + ch * KC + ks * 32);
                acc = __builtin_amdgcn_mfma_f32_16x16x32_bf16(af, bfr, acc, 0, 0, 0);
            }
        }

        // epilogue: C col = lane&15 (our n), row = kg*4 + r (sample in tile)
        int gsz = gsizes[g];
        int n = cw * 16 + lrow;
        float bv = bias[g * MAXGS + n];
        #pragma unroll
        for (int r = 0; r < 4; ++r) {
            int m = m0 + kg * 4 + r;
            if (m < c) {
                int smp = lists[g * BATCH + m];
                out[(size_t)smp * MAXGS + n] = acc[r] + bv;   // padded n: 0+0 == 0
                out[(size_t)(BATCH + smp) * MAXGS + n] = (n < gsz) ? 1.0f : 0.0f;
            }
        }
    }
}

extern "C" void kernel_launch(void* const* d_in, const int* in_sizes, int n_in,
                              void* d_out, int out_size, void* d_ws, size_t ws_size,
                              hipStream_t stream) {
    const float* hidden = (const float*)d_in[0];   // [8192, 8, 2048] f32
    const int*   chosen = (const int*)d_in[1];     // [8192] i32
    const float* W      = (const float*)d_in[2];   // [8, 64, 2048] f32 (zero-padded)
    const float* bias   = (const float*)d_in[3];   // [8, 64] f32 (zero-padded)
    const int*   gs     = (const int*)d_in[4];     // [8] i32
    float* out = (float*)d_out;                    // [8192*64 preds | 8192*64 valid]

    char* ws = (char*)d_ws;
    int* cnt   = (int*)ws;
    int* lists = (int*)(ws + LISTS_OFF);
    unsigned short* Wb = (unsigned short*)(ws + W_OFF);

    init_kernel<<<dim3(1024), dim3(256), 0, stream>>>(W, Wb, cnt);
    bucket_kernel<<<dim3(32), dim3(256), 0, stream>>>(chosen, cnt, lists);
    gemm_kernel<<<dim3(NGRP * (BATCH / TM)), dim3(NTHR), 0, stream>>>(
        hidden, bias, gs, cnt, lists, Wb, out);
}